// Round 2
// baseline (748.353 us; speedup 1.0000x reference)
//
#include <hip/hip_runtime.h>
#include <cstddef>

// Problem constants
#define B_   4
#define NS_  96
#define T_   8
#define H_   256
#define N_   97      // NS + 1
#define NL_  6       // NUM_LAYERS

__device__ __forceinline__ float sigm(float x) { return 1.0f / (1.0f + expf(-x)); }

// ---------------- generic: C[m,n] = sum_k A[m,k]*B[k,n] (+bias[n]), K<=256 ----------------
__global__ void gemm_rowwise(const float* __restrict__ A, const float* __restrict__ Bm,
                             const float* __restrict__ bias, float* __restrict__ C,
                             int K, int Nc) {
    __shared__ float a[256];
    int m = blockIdx.y;
    int t = threadIdx.x;
    if (t < K) a[t] = A[m * K + t];
    __syncthreads();
    int n = blockIdx.x * 256 + t;
    if (n < Nc) {
        float acc = bias ? bias[n] : 0.0f;
        for (int k = 0; k < K; k++) acc = fmaf(a[k], Bm[k * Nc + n], acc);
        C[m * Nc + n] = acc;
    }
}

// ---------------- statement LSTM: embed lookup + x/h projections fused, 2 seqs/block ----------------
__global__ void lstm_fused(const int* __restrict__ ids, const float* __restrict__ embed,
                           const float* __restrict__ Wx, const float* __restrict__ Wh,
                           const float* __restrict__ bs, float* __restrict__ stmt) {
    __shared__ float xb[2][H_];
    __shared__ float hb[2][H_];
    __shared__ int idx[2];
    int t = threadIdx.x;
    int s0 = blockIdx.x * 2;          // sequence index base, 0..383
    float c[2] = {0.0f, 0.0f};
    float hn[2] = {0.0f, 0.0f};
    hb[0][t] = 0.0f;
    hb[1][t] = 0.0f;
    float bsv[4];
#pragma unroll
    for (int g = 0; g < 4; g++) bsv[g] = bs[g * 256 + t];
    for (int step = 0; step < T_; step++) {
        if (t < 2) idx[t] = ids[(s0 + t) * T_ + step];
        __syncthreads();                               // idx + previous hb writes visible
        xb[0][t] = embed[(size_t)idx[0] * H_ + t];
        xb[1][t] = embed[(size_t)idx[1] * H_ + t];
        __syncthreads();                               // xb visible
        float a0[2], a1[2], a2[2], a3[2];
#pragma unroll
        for (int s = 0; s < 2; s++) { a0[s] = bsv[0]; a1[s] = bsv[1]; a2[s] = bsv[2]; a3[s] = bsv[3]; }
#pragma unroll 2
        for (int k = 0; k < H_; k++) {
            float wx0 = Wx[k * 1024 + t];
            float wx1 = Wx[k * 1024 + 256 + t];
            float wx2 = Wx[k * 1024 + 512 + t];
            float wx3 = Wx[k * 1024 + 768 + t];
            float wh0 = Wh[k * 1024 + t];
            float wh1 = Wh[k * 1024 + 256 + t];
            float wh2 = Wh[k * 1024 + 512 + t];
            float wh3 = Wh[k * 1024 + 768 + t];
#pragma unroll
            for (int s = 0; s < 2; s++) {
                float xv = xb[s][k], hv = hb[s][k];
                a0[s] = fmaf(xv, wx0, fmaf(hv, wh0, a0[s]));
                a1[s] = fmaf(xv, wx1, fmaf(hv, wh1, a1[s]));
                a2[s] = fmaf(xv, wx2, fmaf(hv, wh2, a2[s]));
                a3[s] = fmaf(xv, wx3, fmaf(hv, wh3, a3[s]));
            }
        }
#pragma unroll
        for (int s = 0; s < 2; s++) {
            c[s] = sigm(a1[s]) * c[s] + sigm(a0[s]) * tanhf(a2[s]);
            hn[s] = sigm(a3[s]) * tanhf(c[s]);
        }
        __syncthreads();                               // all k-loop reads of hb done
        hb[0][t] = hn[0];
        hb[1][t] = hn[1];
    }
    stmt[(size_t)s0 * H_ + t] = hn[0];
    stmt[(size_t)(s0 + 1) * H_ + t] = hn[1];
}

// ---------------- prefix sums over statements ----------------
__global__ void cumsum_k(const float* __restrict__ stmt, float* __restrict__ pref) {
    int b = blockIdx.x, t = threadIdx.x;
    float run = 0.0f;
    pref[((size_t)b * N_) * H_ + t] = 0.0f;
    for (int n = 1; n < N_; n++) {
        run += stmt[((size_t)b * NS_ + n - 1) * H_ + t];
        pref[((size_t)b * N_ + n) * H_ + t] = run;
    }
}

// ---------------- q = pref@M1 (4H), r = pref@M2 (H), plus transposed r ----------------
__global__ void qr_gemm(const float* __restrict__ pref, const float* __restrict__ M1,
                        const float* __restrict__ M2, float* __restrict__ q,
                        float* __restrict__ r, float* __restrict__ rT) {
    __shared__ float pf[2][H_];
    int t = threadIdx.x;
    int r0 = blockIdx.x * 2;
    for (int rr = 0; rr < 2; rr++) pf[rr][t] = pref[(size_t)(r0 + rr) * H_ + t];
    __syncthreads();
    float aq[2][4] = {};
    float ar[2] = {};
    for (int k = 0; k < H_; k++) {
        float m0 = M1[k * 1024 + t];
        float m1 = M1[k * 1024 + 256 + t];
        float m2 = M1[k * 1024 + 512 + t];
        float m3 = M1[k * 1024 + 768 + t];
        float m4 = M2[k * 256 + t];
#pragma unroll
        for (int rr = 0; rr < 2; rr++) {
            float pv = pf[rr][k];
            aq[rr][0] = fmaf(pv, m0, aq[rr][0]);
            aq[rr][1] = fmaf(pv, m1, aq[rr][1]);
            aq[rr][2] = fmaf(pv, m2, aq[rr][2]);
            aq[rr][3] = fmaf(pv, m3, aq[rr][3]);
            ar[rr] = fmaf(pv, m4, ar[rr]);
        }
    }
    for (int rr = 0; rr < 2; rr++) {
        int row = r0 + rr;
#pragma unroll
        for (int g = 0; g < 4; g++) q[(size_t)row * 1024 + g * 256 + t] = aq[rr][g];
        r[(size_t)row * H_ + t] = ar[rr];
        int b = row / N_, n = row % N_;
        rT[((size_t)b * H_ + t) * 128 + n] = ar[rr];
    }
}

// ---------------- init c/h/p ----------------
__global__ void init_state(const float* __restrict__ ia, const float* __restrict__ ib,
                           float* __restrict__ c0, float* __restrict__ h0,
                           float* __restrict__ p0) {
    int row = blockIdx.x, t = threadIdx.x;
    size_t idx = (size_t)row * H_ + t;
    c0[idx] = ia[t];
    h0[idx] = ib[t];
    if (t == 0) p0[row] = ((row % N_) == 0) ? 1.0f : 0.0f;
}

// ---------------- per-layer: he = h@Wh_e + cz ; hterm = sum relu(h@W_hk+b_hk)*Wd1[:H] ----------------
__global__ void hproj(const float* __restrict__ h, const float* __restrict__ Whe,
                      const float* __restrict__ Whk, const float* __restrict__ bhk,
                      const float* __restrict__ Wd1, const float* __restrict__ cz,
                      float* __restrict__ he, float* __restrict__ hterm) {
    __shared__ float hr[2][H_];
    __shared__ float red[H_];
    int t = threadIdx.x;
    int r0 = blockIdx.x * 2;
    for (int rr = 0; rr < 2; rr++) hr[rr][t] = h[(size_t)(r0 + rr) * H_ + t];
    __syncthreads();
    float ae[2][4] = {};
    float ak[2] = {};
    for (int k = 0; k < H_; k++) {
        float w0 = Whe[k * 1024 + t];
        float w1 = Whe[k * 1024 + 256 + t];
        float w2 = Whe[k * 1024 + 512 + t];
        float w3 = Whe[k * 1024 + 768 + t];
        float wk = Whk[k * 256 + t];
#pragma unroll
        for (int rr = 0; rr < 2; rr++) {
            float hv = hr[rr][k];
            ae[rr][0] = fmaf(hv, w0, ae[rr][0]);
            ae[rr][1] = fmaf(hv, w1, ae[rr][1]);
            ae[rr][2] = fmaf(hv, w2, ae[rr][2]);
            ae[rr][3] = fmaf(hv, w3, ae[rr][3]);
            ak[rr] = fmaf(hv, wk, ak[rr]);
        }
    }
    float czv[4];
#pragma unroll
    for (int g = 0; g < 4; g++) czv[g] = cz[g * 256 + t];
    for (int rr = 0; rr < 2; rr++)
#pragma unroll
        for (int g = 0; g < 4; g++)
            he[(size_t)(r0 + rr) * 1024 + g * 256 + t] = ae[rr][g] + czv[g];
    float bh = bhk[t];
    float wd = Wd1[t];
    for (int rr = 0; rr < 2; rr++) {
        float v = fmaxf(ak[rr] + bh, 0.0f) * wd;
        red[t] = v;
        __syncthreads();
        for (int off = 128; off > 0; off >>= 1) {
            if (t < off) red[t] += red[t + off];
            __syncthreads();
        }
        if (t == 0) hterm[r0 + rr] = red[0];
        __syncthreads();
    }
}

// ---------------- per-layer: logits, masked softmax, w = skip_p * p[i] ----------------
__global__ void logits_softmax(const float* __restrict__ r, const float* __restrict__ rT,
                               const float* __restrict__ ck, const float* __restrict__ Wd1,
                               const float* __restrict__ hterm, const float* __restrict__ p,
                               const int* __restrict__ code_length, int layer,
                               float* __restrict__ w) {
    __shared__ float ri[H_], ckl[H_], wd[H_];
    __shared__ float red[128];
    int t = threadIdx.x;  // 128 threads
    int bi = blockIdx.x;
    int b = bi / N_, i = bi % N_;
    ri[t] = r[(size_t)bi * H_ + t];
    ri[t + 128] = r[(size_t)bi * H_ + t + 128];
    ckl[t] = ck[t];
    ckl[t + 128] = ck[t + 128];
    wd[t] = Wd1[256 + t];
    wd[t + 128] = Wd1[256 + t + 128];
    __syncthreads();
    int len = code_length[b] / T_;
    int j = t;
    bool valid = false;
    if (j < N_) {
        if (layer == 0) valid = (j == 1);
        else if (layer == NL_ - 1) valid = (j == len);
        else valid = (j > i && j <= len) || (j == len);
    }
    float logit = -3.0e38f;
    if (valid) {
        float acc = 0.0f;
        const float* rTb = rT + (size_t)b * H_ * 128 + j;
        for (int h = 0; h < H_; h++) {
            float v = rTb[h * 128] - ri[h] + ckl[h];
            acc = fmaf(fmaxf(v, 0.0f), wd[h], acc);
        }
        logit = acc + hterm[bi];
    }
    red[t] = logit;
    __syncthreads();
    for (int off = 64; off > 0; off >>= 1) {
        if (t < off) red[t] = fmaxf(red[t], red[t + off]);
        __syncthreads();
    }
    float m = red[0];
    __syncthreads();
    float e = valid ? expf(logit - m) : 0.0f;
    red[t] = e;
    __syncthreads();
    for (int off = 64; off > 0; off >>= 1) {
        if (t < off) red[t] += red[t + off];
        __syncthreads();
    }
    float s = red[0];
    if (j < N_) {
        float sp = e / s;
        w[(size_t)bi * N_ + j] = sp * p[bi];
    }
}

// ---------------- per-layer: gated propagation + weighted aggregation per target column j ----------------
__global__ void aggregate(const float* __restrict__ q, const float* __restrict__ he,
                          const float* __restrict__ w, const float* __restrict__ ccur,
                          const float* __restrict__ hcur, float* __restrict__ cnxt,
                          float* __restrict__ hnxt, float* __restrict__ pnxt) {
    __shared__ float qj[1024];
    __shared__ float wcol[128];
    __shared__ float red[128];
    __shared__ float wsum_s;
    int t = threadIdx.x;
    int bj = blockIdx.x;
    int b = bj / N_, j = bj % N_;
    const float* qjp = q + (size_t)bj * 1024;
    qj[t] = qjp[t];
    qj[256 + t] = qjp[256 + t];
    qj[512 + t] = qjp[512 + t];
    qj[768 + t] = qjp[768 + t];
    if (t < 128) wcol[t] = (t < N_) ? w[((size_t)b * N_ + t) * N_ + j] : 0.0f;
    __syncthreads();
    if (t < 128) red[t] = wcol[t];
    __syncthreads();
    for (int off = 64; off > 0; off >>= 1) {
        if (t < off) red[t] += red[t + off];
        __syncthreads();
    }
    if (t == 0) wsum_s = red[0];
    __syncthreads();
    float wsum = wsum_s;
    float accc = 0.0f, acch = 0.0f;
    for (int i = 0; i < N_; i++) {
        float wv = wcol[i];
        if (wv == 0.0f) continue;  // uniform across block (LDS broadcast)
        size_t rowi = (size_t)b * N_ + i;
        if (j > i) {
            const float* qi = q + rowi * 1024;
            const float* hei = he + rowi * 1024;
            float gi = qj[t] - qi[t] + hei[t];
            float gf = qj[256 + t] - qi[256 + t] + hei[256 + t];
            float gg = qj[512 + t] - qi[512 + t] + hei[512 + t];
            float go = qj[768 + t] - qi[768 + t] + hei[768 + t];
            float cc = ccur[rowi * H_ + t];
            float cp = sigm(gf) * cc + sigm(gi) * tanhf(gg);
            float hp = sigm(go) * tanhf(cp);
            accc = fmaf(wv, cp, accc);
            acch = fmaf(wv, hp, acch);
        } else {
            accc = fmaf(wv, ccur[rowi * H_ + t], accc);
            acch = fmaf(wv, hcur[rowi * H_ + t], acch);
        }
    }
    float inv = 1.0f / (wsum + 1e-7f);
    cnxt[(size_t)bj * H_ + t] = accc * inv;
    hnxt[(size_t)bj * H_ + t] = acch * inv;
    if (t == 0) pnxt[bj] = wsum;
}

// ---------------- host launcher ----------------

extern "C" void kernel_launch(void* const* d_in, const int* in_sizes, int n_in,
                              void* d_out, int out_size, void* d_ws, size_t ws_size,
                              hipStream_t stream) {
    const int*   code_statements = (const int*)d_in[0];
    const int*   code_length = (const int*)d_in[1];
    const float* embed = (const float*)d_in[2];
    const float* Wx_s = (const float*)d_in[3];
    const float* Wh_s = (const float*)d_in[4];
    const float* b_s  = (const float*)d_in[5];
    const float* W_se = (const float*)d_in[6];
    const float* b_se = (const float*)d_in[7];
    const float* Wx_e = (const float*)d_in[8];
    const float* Wh_e = (const float*)d_in[9];
    const float* b_e  = (const float*)d_in[10];
    const float* W_hk = (const float*)d_in[11];
    const float* b_hk = (const float*)d_in[12];
    const float* W_sd = (const float*)d_in[13];
    const float* b_sd = (const float*)d_in[14];
    const float* W_d1 = (const float*)d_in[15];
    // d_in[16] = b_d1 : constant shift, softmax-invariant -> unused
    const float* init_a = (const float*)d_in[17];
    const float* init_b = (const float*)d_in[18];
    float* out = (float*)d_out;

    float* wsf = (float*)d_ws;
    size_t off = 0;
    auto alloc = [&](size_t n) { float* p = wsf + off; off += n; return p; };
    float* M1 = alloc(256 * 1024);   // W_se @ Wx_e
    float* M2 = alloc(256 * 256);    // W_se @ W_sd
    float* cz = alloc(1024);         // b_se @ Wx_e + b_e
    float* ck = alloc(256);          // b_se @ W_sd + b_sd
    float* stmt = alloc(384 * 256);
    float* pref = alloc(388 * 256);
    float* q  = alloc(388 * 1024);
    float* r_ = alloc(388 * 256);
    float* rT = alloc(4 * 256 * 128);
    float* he = alloc(388 * 1024);
    float* hterm = alloc(388);
    float* w  = alloc(388 * 97);
    float* p0 = alloc(388);
    float* p1 = alloc(388);
    float* c0 = alloc(388 * 256);
    float* c1 = alloc(388 * 256);
    float* h0 = alloc(388 * 256);
    float* h1 = alloc(388 * 256);
    // total ~7.95 MB of workspace

    // weight prep (all f32)
    gemm_rowwise<<<dim3(4, 256), 256, 0, stream>>>(W_se, Wx_e, nullptr, M1, 256, 1024);
    gemm_rowwise<<<dim3(1, 256), 256, 0, stream>>>(W_se, W_sd, nullptr, M2, 256, 256);
    gemm_rowwise<<<dim3(4, 1), 256, 0, stream>>>(b_se, Wx_e, b_e, cz, 256, 1024);
    gemm_rowwise<<<dim3(1, 1), 256, 0, stream>>>(b_se, W_sd, b_sd, ck, 256, 256);

    // statement encoder
    lstm_fused<<<dim3(192), 256, 0, stream>>>(code_statements, embed, Wx_s, Wh_s, b_s, stmt);
    cumsum_k<<<dim3(4), 256, 0, stream>>>(stmt, pref);
    qr_gemm<<<dim3(194), 256, 0, stream>>>(pref, M1, M2, q, r_, rT);
    init_state<<<dim3(388), 256, 0, stream>>>(init_a, init_b, c0, h0, p0);

    // execution layers
    for (int layer = 0; layer < NL_; layer++) {
        bool odd = (layer & 1);
        float* pc = odd ? p1 : p0;
        float* pn = odd ? p0 : p1;
        float* cc = odd ? c1 : c0;
        float* cn = odd ? c0 : c1;
        float* hc = odd ? h1 : h0;
        float* hn = odd ? h0 : h1;
        if (layer == NL_ - 1) hn = out;  // final h goes straight to d_out
        hproj<<<dim3(194), 256, 0, stream>>>(hc, Wh_e, W_hk, b_hk, W_d1, cz, he, hterm);
        logits_softmax<<<dim3(388), 128, 0, stream>>>(r_, rT, ck, W_d1, hterm, pc,
                                                      code_length, layer, w);
        aggregate<<<dim3(388), 256, 0, stream>>>(q, he, w, cc, hc, cn, hn, pn);
    }
}